// Round 10
// baseline (184.335 us; speedup 1.0000x reference)
//
#include <hip/hip_runtime.h>
#include <math.h>

// ---------------- problem constants ----------------
constexpr int N_A   = 16384;
constexpr int N_P   = 16384;
constexpr int IN_D  = 128;
constexpr int HID   = 64;
constexpr int NH    = 4;    // heads
constexpr int OUTD  = 349;
constexpr int NE    = 262144; // edges per type (2^18)
constexpr int NB    = 64;     // coarse-partition blocks per type (4096 edges each)
constexpr float NEG = 0.2f;

__device__ __forceinline__ float lrelu(float x) { return x > 0.f ? x : NEG * x; }

// ---------------- CSR build: two-level coherent partition ----------------
// coarse histogram: ccnt[(t*NB+blk)*256 + bin]
__global__ __launch_bounds__(256) void k_chist(const int* __restrict__ dW, const int* __restrict__ dC,
                                               const int* __restrict__ dR, int* __restrict__ ccnt) {
    __shared__ int h[256];
    const int t = blockIdx.y;
    const int* __restrict__ d = t == 0 ? dW : t == 1 ? dC : dR;
    const int tid = threadIdx.x;
    h[tid] = 0;
    __syncthreads();
    const int base = blockIdx.x * 4096;
#pragma unroll
    for (int i = 0; i < 16; ++i) {
        int dst = d[base + i * 256 + tid];
        atomicAdd(&h[dst >> 6], 1);
    }
    __syncthreads();
    ccnt[(t * NB + blockIdx.x) * 256 + tid] = h[tid];
}

// single block, 768 threads = (type, bin). totals -> segmented exclusive scan
// -> crow (coarse row) and per-block run offsets coffs.
__global__ __launch_bounds__(768) void k_coffs(const int* __restrict__ ccnt, int* __restrict__ coffs,
                                               int* __restrict__ crow) {
    const int tid = threadIdx.x;
    const int t = tid >> 8, bin = tid & 255;
    int total = 0;
    for (int b = 0; b < NB; ++b) total += ccnt[(t * NB + b) * 256 + bin];
    __shared__ int sc[768];
    sc[tid] = total;
    __syncthreads();
    for (int w = 1; w < 256; w <<= 1) {
        int v = (bin >= w) ? sc[tid - w] : 0;
        __syncthreads();
        sc[tid] += v;
        __syncthreads();
    }
    const int incl = sc[tid];
    const int base = incl - total;       // exclusive prefix within type
    crow[t * 257 + bin] = base;
    if (bin == 255) crow[t * 257 + 256] = incl;   // == NE
    int run = base;
    for (int b = 0; b < NB; ++b) {
        int c = ccnt[(t * NB + b) * 256 + bin];
        coffs[(t * NB + b) * 256 + bin] = run;
        run += c;
    }
}

// coarse scatter into block-private contiguous runs; payload packs
// src (14b) | (dst&63)<<14 into one int.
__global__ __launch_bounds__(256) void k_cscatter(const int* __restrict__ sW, const int* __restrict__ dW,
                                                  const int* __restrict__ sC, const int* __restrict__ dC,
                                                  const int* __restrict__ sR, const int* __restrict__ dR,
                                                  const int* __restrict__ coffs,
                                                  int* __restrict__ ebW, int* __restrict__ ebC,
                                                  int* __restrict__ ebR) {
    __shared__ int cur[256];
    const int t = blockIdx.y;
    const int* __restrict__ sp = t == 0 ? sW : t == 1 ? sC : sR;
    const int* __restrict__ dp = t == 0 ? dW : t == 1 ? dC : dR;
    int* __restrict__ eb = t == 0 ? ebW : t == 1 ? ebC : ebR;
    const int tid = threadIdx.x;
    cur[tid] = coffs[(t * NB + blockIdx.x) * 256 + tid];
    __syncthreads();
    const int base = blockIdx.x * 4096;
#pragma unroll
    for (int i = 0; i < 16; ++i) {
        int e = base + i * 256 + tid;
        int dst = dp[e], src = sp[e];
        int pos = atomicAdd(&cur[dst >> 6], 1);
        eb[pos] = src | ((dst & 63) << 14);
    }
}

// fine pass: one block per (type, coarse bucket). 64-bin counting sort of the
// self-contained region -> final es (contiguous writes) + exact row[].
__global__ __launch_bounds__(256) void k_fine(const int* __restrict__ crow,
                                              const int* __restrict__ ebW, const int* __restrict__ ebC,
                                              const int* __restrict__ ebR,
                                              int* __restrict__ row,
                                              int* __restrict__ esW, int* __restrict__ esC,
                                              int* __restrict__ esR) {
    __shared__ int bins[64], exc[64], cur[64];
    const int t = blockIdx.y, cb = blockIdx.x, tid = threadIdx.x;
    const int* __restrict__ eb = t == 0 ? ebW : t == 1 ? ebC : ebR;
    int* __restrict__ es = t == 0 ? esW : t == 1 ? esC : esR;
    const int lo = crow[t * 257 + cb], hi = crow[t * 257 + cb + 1];
    if (tid < 64) bins[tid] = 0;
    __syncthreads();
    for (int e = lo + tid; e < hi; e += 256) atomicAdd(&bins[eb[e] >> 14], 1);
    __syncthreads();
    if (tid == 0) {
        int r = 0;
#pragma unroll
        for (int j = 0; j < 64; ++j) { exc[j] = r; cur[j] = r; r += bins[j]; }
    }
    __syncthreads();
    if (tid < 64) row[t * 16385 + cb * 64 + tid] = lo + exc[tid];
    if (tid == 0 && cb == 255) row[t * 16385 + 16384] = crow[t * 257 + 256];
    for (int e = lo + tid; e < hi; e += 256) {
        int v = eb[e];
        int pos = atomicAdd(&cur[v >> 14], 1);
        es[lo + pos] = v & 16383;
    }
}

// ---------------- batched GEMM (X@W) + el/er head reductions -------
struct GemmJobs {
    const float* X[5];  const float* W[5];  const float* NT[5];
    float* F[5];        float* EL[5];       float* ER[5];
    const float* AL[5]; const float* AR[5];
};

template <int K, int RELU>
__global__ __launch_bounds__(256) void k_gemm(GemmJobs j) {
    __shared__ float Wc[32 * 64];
    __shared__ float XT[32][68];

    const float* __restrict__ X;  const float* __restrict__ Wp;  const float* __restrict__ NTp;
    float* __restrict__ F;  float* __restrict__ EL;  float* __restrict__ ER;
    const float* __restrict__ AL; const float* __restrict__ AR;
    switch (blockIdx.z) {                         // block-uniform, static indices
      case 0: X=j.X[0]; Wp=j.W[0]; NTp=j.NT[0]; F=j.F[0]; EL=j.EL[0]; ER=j.ER[0]; AL=j.AL[0]; AR=j.AR[0]; break;
      case 1: X=j.X[1]; Wp=j.W[1]; NTp=j.NT[1]; F=j.F[1]; EL=j.EL[1]; ER=j.ER[1]; AL=j.AL[1]; AR=j.AR[1]; break;
      case 2: X=j.X[2]; Wp=j.W[2]; NTp=j.NT[2]; F=j.F[2]; EL=j.EL[2]; ER=j.ER[2]; AL=j.AL[2]; AR=j.AR[2]; break;
      case 3: X=j.X[3]; Wp=j.W[3]; NTp=j.NT[3]; F=j.F[3]; EL=j.EL[3]; ER=j.ER[3]; AL=j.AL[3]; AR=j.AR[3]; break;
      default: X=j.X[4]; Wp=j.W[4]; NTp=j.NT[4]; F=j.F[4]; EL=j.EL[4]; ER=j.ER[4]; AL=j.AL[4]; AR=j.AR[4]; break;
    }

    const int tid = threadIdx.x;
    const int tx  = tid & 15;     // col group: cols tx*4..tx*4+3
    const int rg  = tid >> 4;     // row group: rows rg*4..rg*4+3
    const int r0  = blockIdx.x * 64;

    float acc[4][4] = {};

    for (int kc = 0; kc < K; kc += 32) {
        __syncthreads();
        // stage W chunk (32x64)
#pragma unroll
        for (int it = 0; it < 2; ++it) {
            int idx = tid * 4 + it * 1024;
            int k = idx >> 6, c = idx & 63;
            *(float4*)(Wc + idx) = *(const float4*)(Wp + (size_t)(kc + k) * 64 + c);
        }
        // stage X chunk transposed (XT[k][row])
#pragma unroll
        for (int it = 0; it < 2; ++it) {
            int idx = tid * 4 + it * 1024;
            int row = idx >> 5, col = idx & 31;
            float4 v = *(const float4*)(X + (size_t)(r0 + row) * K + kc + col);
            if (RELU) {
                v.x = fmaxf(v.x, 0.f); v.y = fmaxf(v.y, 0.f);
                v.z = fmaxf(v.z, 0.f); v.w = fmaxf(v.w, 0.f);
            }
            if (NTp) {
                float4 s = *(const float4*)(NTp + kc + col);
                v.x *= s.x; v.y *= s.y; v.z *= s.z; v.w *= s.w;
            }
            XT[col + 0][row] = v.x;
            XT[col + 1][row] = v.y;
            XT[col + 2][row] = v.z;
            XT[col + 3][row] = v.w;
        }
        __syncthreads();
#pragma unroll
        for (int kk = 0; kk < 32; ++kk) {
            float4 a4 = *(const float4*)(&XT[kk][rg * 4]);
            float4 w4 = *(const float4*)(Wc + kk * 64 + tx * 4);
            acc[0][0] = fmaf(a4.x, w4.x, acc[0][0]); acc[0][1] = fmaf(a4.x, w4.y, acc[0][1]);
            acc[0][2] = fmaf(a4.x, w4.z, acc[0][2]); acc[0][3] = fmaf(a4.x, w4.w, acc[0][3]);
            acc[1][0] = fmaf(a4.y, w4.x, acc[1][0]); acc[1][1] = fmaf(a4.y, w4.y, acc[1][1]);
            acc[1][2] = fmaf(a4.y, w4.z, acc[1][2]); acc[1][3] = fmaf(a4.y, w4.w, acc[1][3]);
            acc[2][0] = fmaf(a4.z, w4.x, acc[2][0]); acc[2][1] = fmaf(a4.z, w4.y, acc[2][1]);
            acc[2][2] = fmaf(a4.z, w4.z, acc[2][2]); acc[2][3] = fmaf(a4.z, w4.w, acc[2][3]);
            acc[3][0] = fmaf(a4.w, w4.x, acc[3][0]); acc[3][1] = fmaf(a4.w, w4.y, acc[3][1]);
            acc[3][2] = fmaf(a4.w, w4.z, acc[3][2]); acc[3][3] = fmaf(a4.w, w4.w, acc[3][3]);
        }
    }

    if (F) {
#pragma unroll
        for (int i = 0; i < 4; ++i) {
            size_t n = (size_t)r0 + rg * 4 + i;
            *(float4*)(F + n * 64 + tx * 4) =
                make_float4(acc[i][0], acc[i][1], acc[i][2], acc[i][3]);
        }
    }
    // el/er: thread's 4 cols belong to head tx>>2; reduce over the 4 lanes of
    // the head group (lane bits 0,1) via shfl_xor.
    if (EL) {
        float4 alv = ((const float4*)AL)[tx];
#pragma unroll
        for (int i = 0; i < 4; ++i) {
            float p = acc[i][0] * alv.x + acc[i][1] * alv.y +
                      acc[i][2] * alv.z + acc[i][3] * alv.w;
            p += __shfl_xor(p, 1, 64);
            p += __shfl_xor(p, 2, 64);
            if ((tx & 3) == 0) EL[((size_t)r0 + rg * 4 + i) * 4 + (tx >> 2)] = p;
        }
    }
    if (ER) {
        float4 arv = ((const float4*)AR)[tx];
#pragma unroll
        for (int i = 0; i < 4; ++i) {
            float p = acc[i][0] * arv.x + acc[i][1] * arv.y +
                      acc[i][2] * arv.z + acc[i][3] * arv.w;
            p += __shfl_xor(p, 1, 64);
            p += __shfl_xor(p, 2, 64);
            if ((tx & 3) == 0) ER[((size_t)r0 + rg * 4 + i) * 4 + (tx >> 2)] = p;
        }
    }
}

// ---------------- per-destination gather aggregation (no atomics) ----------
// Wave layout: lane = (edge slot 0..3) x (col-group 0..15). 4 edges processed
// in parallel; each lane owns 4 consecutive cols (one head: h = (lane&15)>>2)
// and accumulates alpha*fs as a float4. ZERO shuffles in the hot loop (the old
// 16-edge broadcast scheme spent 2 ds_bpermute per edge); one 2-step shfl_xor
// slot-reduction at the end. Single-pass softmax (shift-invariant, |e|<~6).
struct AggType { const int* row; const int* es; const float* el; const float* er; const float* fs; };
struct AggArgs { AggType t[3]; const float* b; float* op; float* oa; };

__device__ __forceinline__ float4 agg4(const int* __restrict__ rowv, const int* __restrict__ es,
                                       const float* __restrict__ el, const float* __restrict__ er,
                                       const float* __restrict__ fs, int d, int lane,
                                       float* denOut) {
    float4 acc = make_float4(0.f, 0.f, 0.f, 0.f);
    float den = 0.f;
    int start = rowv[d], deg = rowv[d + 1] - start;
    if (deg > 0) {
        const int slot = lane >> 4;        // edge slot
        const int c16  = lane & 15;        // col group: cols c16*4..c16*4+3
        const int h    = c16 >> 2;         // head of those cols
        const float rh = er[(size_t)d * 4 + h];
        for (int e0 = 0; e0 < deg; e0 += 4) {
            int o = e0 + slot;
            int sn = es[start + (o < deg ? o : 0)];
            float wv = 0.f;
            if (o < deg) wv = __expf(lrelu(el[(size_t)sn * 4 + h] + rh));
            den += wv;
            float4 f4 = *(const float4*)(fs + (size_t)sn * 64 + c16 * 4);
            acc.x = fmaf(wv, f4.x, acc.x);
            acc.y = fmaf(wv, f4.y, acc.y);
            acc.z = fmaf(wv, f4.z, acc.z);
            acc.w = fmaf(wv, f4.w, acc.w);
        }
    }
    *denOut = den;
    return acc;
}

__device__ __forceinline__ float4 slot_reduce_norm(float4 acc, float den) {
#pragma unroll
    for (int w = 16; w < 64; w <<= 1) {
        den   += __shfl_xor(den, w, 64);
        acc.x += __shfl_xor(acc.x, w, 64);
        acc.y += __shfl_xor(acc.y, w, 64);
        acc.z += __shfl_xor(acc.z, w, 64);
        acc.w += __shfl_xor(acc.w, w, 64);
    }
    float inv = 1.f / fmaxf(den, 1e-9f);
    acc.x *= inv; acc.y *= inv; acc.z *= inv; acc.w *= inv;
    return acc;
}

__global__ __launch_bounds__(256) void k_agg(AggArgs A) {
    int wid = (blockIdx.x * 256 + threadIdx.x) >> 6;  // one wave per dst node
    int lane = threadIdx.x & 63;
    int c16 = lane & 15;
    if (wid < N_P) {
        float d0, d1;
        float4 a0 = agg4(A.t[0].row, A.t[0].es, A.t[0].el, A.t[0].er, A.t[0].fs, wid, lane, &d0);
        float4 a1 = agg4(A.t[1].row, A.t[1].es, A.t[1].el, A.t[1].er, A.t[1].fs, wid, lane, &d1);
        a0 = slot_reduce_norm(a0, d0);
        a1 = slot_reduce_norm(a1, d1);
        if (lane < 16) {
            float4 b0 = *(const float4*)(A.b + c16 * 4);
            float4 b1 = *(const float4*)(A.b + 64 + c16 * 4);
            float4 o = make_float4(a0.x + a1.x + b0.x + b1.x,
                                   a0.y + a1.y + b0.y + b1.y,
                                   a0.z + a1.z + b0.z + b1.z,
                                   a0.w + a1.w + b0.w + b1.w);
            *(float4*)(A.op + (size_t)wid * 64 + c16 * 4) = o;
        }
    } else {
        int d = wid - N_P;
        float d2;
        float4 a2 = agg4(A.t[2].row, A.t[2].es, A.t[2].el, A.t[2].er, A.t[2].fs, d, lane, &d2);
        a2 = slot_reduce_norm(a2, d2);
        if (lane < 16) {
            float4 b2 = *(const float4*)(A.b + 128 + c16 * 4);
            float4 o = make_float4(a2.x + b2.x, a2.y + b2.y, a2.z + b2.z, a2.w + b2.w);
            *(float4*)(A.oa + (size_t)d * 64 + c16 * 4) = o;
        }
    }
}

// ---------------- hf build: h2 = h1 + C, row l2-normalize, concat ------------
__global__ __launch_bounds__(256) void k_hf(const float* __restrict__ h1, float* __restrict__ hf,
                                            const float* __restrict__ ln1gb,
                                            const float* __restrict__ aw, const float* __restrict__ ab,
                                            const float* __restrict__ ln2gb,
                                            const float* __restrict__ fw1, const float* __restrict__ fb1,
                                            const float* __restrict__ fw2, const float* __restrict__ fb2) {
    __shared__ float Cs;
    if (threadIdx.x == 0) {
        // LN over size-1 axis -> exactly its bias term
        float y1 = ln1gb[1];
        float v  = y1 * aw[2] + ab[2];          // v constant; softmax uniform -> o = v
        float o  = v * aw[3] + ab[3];
        float y2 = ln2gb[1];
        float f  = fb2[0];
#pragma unroll
        for (int q = 0; q < 16; ++q) {
            float zz = y2 * fw1[q] + fb1[q];
            f += 0.5f * zz * (1.f + erff(zz * 0.70710678118654752f)) * fw2[q];
        }
        Cs = o + f;
    }
    __syncthreads();
    float C = Cs;
    int lane = threadIdx.x & 63;
    int row  = blockIdx.x * 4 + (threadIdx.x >> 6);
    float v1 = h1[(size_t)row * 64 + lane];
    float s1 = v1 * v1;
#pragma unroll
    for (int w = 1; w < 64; w <<= 1) s1 += __shfl_xor(s1, w, 64);
    float o1 = v1 / fmaxf(sqrtf(s1), 1e-12f);
    float v2 = v1 + C;
    float s2 = v2 * v2;
#pragma unroll
    for (int w = 1; w < 64; w <<= 1) s2 += __shfl_xor(s2, w, 64);
    float o2 = v2 / fmaxf(sqrtf(s2), 1e-12f);
    hf[(size_t)row * 128 + lane]      = o1;
    hf[(size_t)row * 128 + 64 + lane] = o2;
}

// ---------------- final GEMM: out = hf(16384x128) @ linW(128x349) + linb -----
__global__ __launch_bounds__(256) void k_gemm_out(const float* __restrict__ X,
                                                  const float* __restrict__ W,
                                                  const float* __restrict__ bias,
                                                  float* __restrict__ out) {
    __shared__ float Wc[32 * 64];
    __shared__ float XT[32][68];
    const int tid = threadIdx.x;
    const int tx  = tid & 15;
    const int rg  = tid >> 4;
    const int r0  = blockIdx.x * 64;
    const int c0  = blockIdx.y * 64;

    float acc[4][4] = {};

    for (int kc = 0; kc < 128; kc += 32) {
        __syncthreads();
#pragma unroll
        for (int it = 0; it < 2; ++it) {
            int idx = tid * 4 + it * 1024;
            int k = idx >> 6, c = idx & 63;
            int gk = kc + k;
            float4 v;
            int gc = c0 + c;
            v.x = (gc + 0 < OUTD) ? W[(size_t)gk * OUTD + gc + 0] : 0.f;
            v.y = (gc + 1 < OUTD) ? W[(size_t)gk * OUTD + gc + 1] : 0.f;
            v.z = (gc + 2 < OUTD) ? W[(size_t)gk * OUTD + gc + 2] : 0.f;
            v.w = (gc + 3 < OUTD) ? W[(size_t)gk * OUTD + gc + 3] : 0.f;
            *(float4*)(Wc + idx) = v;
        }
#pragma unroll
        for (int it = 0; it < 2; ++it) {
            int idx = tid * 4 + it * 1024;
            int row = idx >> 5, col = idx & 31;
            float4 v = *(const float4*)(X + (size_t)(r0 + row) * 128 + kc + col);
            XT[col + 0][row] = v.x;
            XT[col + 1][row] = v.y;
            XT[col + 2][row] = v.z;
            XT[col + 3][row] = v.w;
        }
        __syncthreads();
#pragma unroll
        for (int kk = 0; kk < 32; ++kk) {
            float4 a4 = *(const float4*)(&XT[kk][rg * 4]);
            float4 w4 = *(const float4*)(Wc + kk * 64 + tx * 4);
            acc[0][0] = fmaf(a4.x, w4.x, acc[0][0]); acc[0][1] = fmaf(a4.x, w4.y, acc[0][1]);
            acc[0][2] = fmaf(a4.x, w4.z, acc[0][2]); acc[0][3] = fmaf(a4.x, w4.w, acc[0][3]);
            acc[1][0] = fmaf(a4.y, w4.x, acc[1][0]); acc[1][1] = fmaf(a4.y, w4.y, acc[1][1]);
            acc[1][2] = fmaf(a4.y, w4.z, acc[1][2]); acc[1][3] = fmaf(a4.y, w4.w, acc[1][3]);
            acc[2][0] = fmaf(a4.z, w4.x, acc[2][0]); acc[2][1] = fmaf(a4.z, w4.y, acc[2][1]);
            acc[2][2] = fmaf(a4.z, w4.z, acc[2][2]); acc[2][3] = fmaf(a4.z, w4.w, acc[2][3]);
            acc[3][0] = fmaf(a4.w, w4.x, acc[3][0]); acc[3][1] = fmaf(a4.w, w4.y, acc[3][1]);
            acc[3][2] = fmaf(a4.w, w4.z, acc[3][2]); acc[3][3] = fmaf(a4.w, w4.w, acc[3][3]);
        }
    }

    float b4[4];
#pragma unroll
    for (int q = 0; q < 4; ++q) {
        int c = c0 + tx * 4 + q;
        b4[q] = (c < OUTD) ? bias[c] : 0.f;
    }
#pragma unroll
    for (int i = 0; i < 4; ++i) {
        size_t n = (size_t)r0 + rg * 4 + i;
#pragma unroll
        for (int q = 0; q < 4; ++q) {
            int c = c0 + tx * 4 + q;
            if (c < OUTD) out[n * OUTD + c] = acc[i][q] + b4[q];
        }
    }
}

// ---------------- host ----------------
extern "C" void kernel_launch(void* const* d_in, const int* in_sizes, int n_in,
                              void* d_out, int out_size, void* d_ws, size_t ws_size,
                              hipStream_t stream) {
    const float* x_author = (const float*)d_in[0];
    const float* x_paper  = (const float*)d_in[1];
    const float* ntype    = (const float*)d_in[2];
    const float* W0  = (const float*)d_in[3];
    const float* al0 = (const float*)d_in[4];
    const float* ar0 = (const float*)d_in[5];
    const float* b0  = (const float*)d_in[6];
    const float* W1  = (const float*)d_in[7];
    const float* al1 = (const float*)d_in[8];
    const float* ar1 = (const float*)d_in[9];
    const float* b1  = (const float*)d_in[10];
    const float* ln1gb = (const float*)d_in[11];
    const float* attw  = (const float*)d_in[12];
    const float* attb  = (const float*)d_in[13];
    const float* ln2gb = (const float*)d_in[14];
    const float* fw1 = (const float*)d_in[15];
    const float* fb1 = (const float*)d_in[16];
    const float* fw2 = (const float*)d_in[17];
    const float* fb2 = (const float*)d_in[18];
    const float* linW = (const float*)d_in[19];
    const float* linb = (const float*)d_in[20];
    const int* srcW = (const int*)d_in[21];
    const int* dstW = (const int*)d_in[22];
    const int* srcC = (const int*)d_in[23];
    const int* dstC = (const int*)d_in[24];
    const int* srcR = (const int*)d_in[25];
    const int* dstR = (const int*)d_in[26];
    float* out = (float*)d_out;

    // ---- workspace carve-up ----
    float* ws = (float*)d_ws;
    size_t off = 0;
    float* fsW = ws + off; off += (size_t)N_A * HID;
    float* fsC = ws + off; off += (size_t)N_P * HID;
    float* fsR = ws + off; off += (size_t)N_P * HID;
    float* elw = ws + off; off += (size_t)N_A * NH;
    float* erw = ws + off; off += (size_t)N_P * NH;
    float* elc = ws + off; off += (size_t)N_P * NH;
    float* erc = ws + off; off += (size_t)N_P * NH;
    float* elr = ws + off; off += (size_t)N_P * NH;
    float* err = ws + off; off += (size_t)N_A * NH;
    float* oa0 = ws + off; off += (size_t)N_A * HID;
    float* op0 = ws + off; off += (size_t)N_P * HID;
    float* oa1 = ws + off; off += (size_t)N_A * HID;
    float* op1 = ws + off; off += (size_t)N_P * HID;
    float* hf  = ws + off; off += (size_t)N_P * 2 * HID;
    int* ccnt  = (int*)(ws + off); off += 3 * NB * 256;
    int* coffs = (int*)(ws + off); off += 3 * NB * 256;
    int* crow  = (int*)(ws + off); off += 3 * 257 + 1;
    int* row   = (int*)(ws + off); off += 3 * 16385 + 1;
    int* ebW  = (int*)(ws + off); off += NE;
    int* ebC  = (int*)(ws + off); off += NE;
    int* ebR  = (int*)(ws + off); off += NE;
    int* esW  = (int*)(ws + off); off += NE;
    int* esC  = (int*)(ws + off); off += NE;
    int* esR  = (int*)(ws + off); off += NE;

    const int* rowW = row;
    const int* rowC = row + 16385;
    const int* rowR = row + 2 * 16385;

    const float* ntA = ntype;            // author scale row (128)
    const float* ntP = ntype + IN_D;     // paper scale row

    // ---- layer job tables (layer 0 reads raw x, scaled by NT on load) ----
    GemmJobs j0{};
    j0.X[0] = x_author; j0.W[0] = W0;                  j0.NT[0] = ntA;
    j0.F[0] = fsW; j0.EL[0] = elw; j0.ER[0] = nullptr; j0.AL[0] = al0;       j0.AR[0] = nullptr;
    j0.X[1] = x_paper;  j0.W[1] = W0;                  j0.NT[1] = ntP;
    j0.F[1] = nullptr; j0.EL[1] = nullptr; j0.ER[1] = erw; j0.AL[1] = nullptr; j0.AR[1] = ar0;
    j0.X[2] = x_paper;  j0.W[2] = W0 + IN_D * HID;     j0.NT[2] = ntP;
    j0.F[2] = fsC; j0.EL[2] = elc; j0.ER[2] = erc;     j0.AL[2] = al0 + 64;  j0.AR[2] = ar0 + 64;
    j0.X[3] = x_paper;  j0.W[3] = W0 + 2 * IN_D * HID; j0.NT[3] = ntP;
    j0.F[3] = fsR; j0.EL[3] = elr; j0.ER[3] = nullptr; j0.AL[3] = al0 + 128; j0.AR[3] = nullptr;
    j0.X[4] = x_author; j0.W[4] = W0 + 2 * IN_D * HID; j0.NT[4] = ntA;
    j0.F[4] = nullptr; j0.EL[4] = nullptr; j0.ER[4] = err; j0.AL[4] = nullptr; j0.AR[4] = ar0 + 128;

    GemmJobs j1{};
    j1.X[0] = oa0; j1.W[0] = W1;                   j1.NT[0] = nullptr;
    j1.F[0] = fsW; j1.EL[0] = elw; j1.ER[0] = nullptr; j1.AL[0] = al1;       j1.AR[0] = nullptr;
    j1.X[1] = op0; j1.W[1] = W1;                   j1.NT[1] = nullptr;
    j1.F[1] = nullptr; j1.EL[1] = nullptr; j1.ER[1] = erw; j1.AL[1] = nullptr; j1.AR[1] = ar1;
    j1.X[2] = op0; j1.W[2] = W1 + HID * HID;       j1.NT[2] = nullptr;
    j1.F[2] = fsC; j1.EL[2] = elc; j1.ER[2] = erc;     j1.AL[2] = al1 + 64;  j1.AR[2] = ar1 + 64;
    j1.X[3] = op0; j1.W[3] = W1 + 2 * HID * HID;   j1.NT[3] = nullptr;
    j1.F[3] = fsR; j1.EL[3] = elr; j1.ER[3] = nullptr; j1.AL[3] = al1 + 128; j1.AR[3] = nullptr;
    j1.X[4] = oa0; j1.W[4] = W1 + 2 * HID * HID;   j1.NT[4] = nullptr;
    j1.F[4] = nullptr; j1.EL[4] = nullptr; j1.ER[4] = err; j1.AL[4] = nullptr; j1.AR[4] = ar1 + 128;

    AggArgs a0{};
    a0.t[0] = {rowW, esW, elw, erw, fsW};
    a0.t[1] = {rowC, esC, elc, erc, fsC};
    a0.t[2] = {rowR, esR, elr, err, fsR};
    a0.b = b0; a0.op = op0; a0.oa = oa0;
    AggArgs a1 = a0;
    a1.b = b1; a1.op = op1; a1.oa = oa1;

    // ---- launches ----
    // CSR build (edge lists constant across layers): two-level partition
    k_chist<<<dim3(NB, 3), 256, 0, stream>>>(dstW, dstC, dstR, ccnt);
    k_coffs<<<1, 768, 0, stream>>>(ccnt, coffs, crow);
    k_cscatter<<<dim3(NB, 3), 256, 0, stream>>>(srcW, dstW, srcC, dstC, srcR, dstR,
                                                coffs, ebW, ebC, ebR);
    k_fine<<<dim3(256, 3), 256, 0, stream>>>(crow, ebW, ebC, ebR, row, esW, esC, esR);

    // layer 0 (ntype scale folded into X load)
    k_gemm<IN_D, 0><<<dim3(N_A / 64, 1, 5), 256, 0, stream>>>(j0);
    k_agg<<<(N_P + N_A) / 4, 256, 0, stream>>>(a0);

    // layer 1 (relu folded into GEMM X loads)
    k_gemm<HID, 1><<<dim3(N_A / 64, 1, 5), 256, 0, stream>>>(j1);
    k_agg<<<(N_P + N_A) / 4, 256, 0, stream>>>(a1);

    // epilogue
    k_hf<<<N_P / 4, 256, 0, stream>>>(op1, hf, ln1gb, attw, attb, ln2gb, fw1, fb1, fw2, fb2);
    k_gemm_out<<<dim3(N_P / 64, (OUTD + 63) / 64), 256, 0, stream>>>(hf, linW, linb, out);
}

// Round 11
// 160.111 us; speedup vs baseline: 1.1513x; 1.1513x over previous
//
#include <hip/hip_runtime.h>
#include <math.h>

// ---------------- problem constants ----------------
constexpr int N_A   = 16384;
constexpr int N_P   = 16384;
constexpr int IN_D  = 128;
constexpr int HID   = 64;
constexpr int NH    = 4;    // heads
constexpr int OUTD  = 349;
constexpr int NE    = 262144; // edges per type (2^18)
constexpr int NB    = 64;     // coarse-partition blocks per type (4096 edges each)
constexpr float NEG = 0.2f;

__device__ __forceinline__ float lrelu(float x) { return x > 0.f ? x : NEG * x; }

// ---------------- CSR build: two-level coherent partition ----------------
// coarse histogram: ccnt[(t*NB+blk)*256 + bin]
__global__ __launch_bounds__(256) void k_chist(const int* __restrict__ dW, const int* __restrict__ dC,
                                               const int* __restrict__ dR, int* __restrict__ ccnt) {
    __shared__ int h[256];
    const int t = blockIdx.y;
    const int* __restrict__ d = t == 0 ? dW : t == 1 ? dC : dR;
    const int tid = threadIdx.x;
    h[tid] = 0;
    __syncthreads();
    const int base = blockIdx.x * 4096;
#pragma unroll
    for (int i = 0; i < 16; ++i) {
        int dst = d[base + i * 256 + tid];
        atomicAdd(&h[dst >> 6], 1);
    }
    __syncthreads();
    ccnt[(t * NB + blockIdx.x) * 256 + tid] = h[tid];
}

// single block, 768 threads = (type, bin). totals -> segmented exclusive scan
// -> crow (coarse row) and per-block run offsets coffs.
__global__ __launch_bounds__(768) void k_coffs(const int* __restrict__ ccnt, int* __restrict__ coffs,
                                               int* __restrict__ crow) {
    const int tid = threadIdx.x;
    const int t = tid >> 8, bin = tid & 255;
    int total = 0;
    for (int b = 0; b < NB; ++b) total += ccnt[(t * NB + b) * 256 + bin];
    __shared__ int sc[768];
    sc[tid] = total;
    __syncthreads();
    for (int w = 1; w < 256; w <<= 1) {
        int v = (bin >= w) ? sc[tid - w] : 0;
        __syncthreads();
        sc[tid] += v;
        __syncthreads();
    }
    const int incl = sc[tid];
    const int base = incl - total;       // exclusive prefix within type
    crow[t * 257 + bin] = base;
    if (bin == 255) crow[t * 257 + 256] = incl;   // == NE
    int run = base;
    for (int b = 0; b < NB; ++b) {
        int c = ccnt[(t * NB + b) * 256 + bin];
        coffs[(t * NB + b) * 256 + bin] = run;
        run += c;
    }
}

// coarse scatter into block-private contiguous runs; payload packs
// src (14b) | (dst&63)<<14 into one int.
__global__ __launch_bounds__(256) void k_cscatter(const int* __restrict__ sW, const int* __restrict__ dW,
                                                  const int* __restrict__ sC, const int* __restrict__ dC,
                                                  const int* __restrict__ sR, const int* __restrict__ dR,
                                                  const int* __restrict__ coffs,
                                                  int* __restrict__ ebW, int* __restrict__ ebC,
                                                  int* __restrict__ ebR) {
    __shared__ int cur[256];
    const int t = blockIdx.y;
    const int* __restrict__ sp = t == 0 ? sW : t == 1 ? sC : sR;
    const int* __restrict__ dp = t == 0 ? dW : t == 1 ? dC : dR;
    int* __restrict__ eb = t == 0 ? ebW : t == 1 ? ebC : ebR;
    const int tid = threadIdx.x;
    cur[tid] = coffs[(t * NB + blockIdx.x) * 256 + tid];
    __syncthreads();
    const int base = blockIdx.x * 4096;
#pragma unroll
    for (int i = 0; i < 16; ++i) {
        int e = base + i * 256 + tid;
        int dst = dp[e], src = sp[e];
        int pos = atomicAdd(&cur[dst >> 6], 1);
        eb[pos] = src | ((dst & 63) << 14);
    }
}

// fine pass: one block per (type, coarse bucket). 64-bin counting sort of the
// self-contained region -> final es (contiguous writes) + exact row[].
__global__ __launch_bounds__(256) void k_fine(const int* __restrict__ crow,
                                              const int* __restrict__ ebW, const int* __restrict__ ebC,
                                              const int* __restrict__ ebR,
                                              int* __restrict__ row,
                                              int* __restrict__ esW, int* __restrict__ esC,
                                              int* __restrict__ esR) {
    __shared__ int bins[64], exc[64], cur[64];
    const int t = blockIdx.y, cb = blockIdx.x, tid = threadIdx.x;
    const int* __restrict__ eb = t == 0 ? ebW : t == 1 ? ebC : ebR;
    int* __restrict__ es = t == 0 ? esW : t == 1 ? esC : esR;
    const int lo = crow[t * 257 + cb], hi = crow[t * 257 + cb + 1];
    if (tid < 64) bins[tid] = 0;
    __syncthreads();
    for (int e = lo + tid; e < hi; e += 256) atomicAdd(&bins[eb[e] >> 14], 1);
    __syncthreads();
    if (tid == 0) {
        int r = 0;
#pragma unroll
        for (int j = 0; j < 64; ++j) { exc[j] = r; cur[j] = r; r += bins[j]; }
    }
    __syncthreads();
    if (tid < 64) row[t * 16385 + cb * 64 + tid] = lo + exc[tid];
    if (tid == 0 && cb == 255) row[t * 16385 + 16384] = crow[t * 257 + 256];
    for (int e = lo + tid; e < hi; e += 256) {
        int v = eb[e];
        int pos = atomicAdd(&cur[v >> 14], 1);
        es[lo + pos] = v & 16383;
    }
}

// ---------------- batched GEMM (X@W) + el/er head reductions -------
struct GemmJobs {
    const float* X[5];  const float* W[5];  const float* NT[5];
    float* F[5];        float* EL[5];       float* ER[5];
    const float* AL[5]; const float* AR[5];
};

template <int K, int RELU>
__global__ __launch_bounds__(256) void k_gemm(GemmJobs j) {
    __shared__ float Wc[32 * 64];
    __shared__ float XT[32][68];

    const float* __restrict__ X;  const float* __restrict__ Wp;  const float* __restrict__ NTp;
    float* __restrict__ F;  float* __restrict__ EL;  float* __restrict__ ER;
    const float* __restrict__ AL; const float* __restrict__ AR;
    switch (blockIdx.z) {                         // block-uniform, static indices
      case 0: X=j.X[0]; Wp=j.W[0]; NTp=j.NT[0]; F=j.F[0]; EL=j.EL[0]; ER=j.ER[0]; AL=j.AL[0]; AR=j.AR[0]; break;
      case 1: X=j.X[1]; Wp=j.W[1]; NTp=j.NT[1]; F=j.F[1]; EL=j.EL[1]; ER=j.ER[1]; AL=j.AL[1]; AR=j.AR[1]; break;
      case 2: X=j.X[2]; Wp=j.W[2]; NTp=j.NT[2]; F=j.F[2]; EL=j.EL[2]; ER=j.ER[2]; AL=j.AL[2]; AR=j.AR[2]; break;
      case 3: X=j.X[3]; Wp=j.W[3]; NTp=j.NT[3]; F=j.F[3]; EL=j.EL[3]; ER=j.ER[3]; AL=j.AL[3]; AR=j.AR[3]; break;
      default: X=j.X[4]; Wp=j.W[4]; NTp=j.NT[4]; F=j.F[4]; EL=j.EL[4]; ER=j.ER[4]; AL=j.AL[4]; AR=j.AR[4]; break;
    }

    const int tid = threadIdx.x;
    const int tx  = tid & 15;     // col group: cols tx*4..tx*4+3
    const int rg  = tid >> 4;     // row group: rows rg*4..rg*4+3
    const int r0  = blockIdx.x * 64;

    float acc[4][4] = {};

    for (int kc = 0; kc < K; kc += 32) {
        __syncthreads();
        // stage W chunk (32x64)
#pragma unroll
        for (int it = 0; it < 2; ++it) {
            int idx = tid * 4 + it * 1024;
            int k = idx >> 6, c = idx & 63;
            *(float4*)(Wc + idx) = *(const float4*)(Wp + (size_t)(kc + k) * 64 + c);
        }
        // stage X chunk transposed (XT[k][row])
#pragma unroll
        for (int it = 0; it < 2; ++it) {
            int idx = tid * 4 + it * 1024;
            int row = idx >> 5, col = idx & 31;
            float4 v = *(const float4*)(X + (size_t)(r0 + row) * K + kc + col);
            if (RELU) {
                v.x = fmaxf(v.x, 0.f); v.y = fmaxf(v.y, 0.f);
                v.z = fmaxf(v.z, 0.f); v.w = fmaxf(v.w, 0.f);
            }
            if (NTp) {
                float4 s = *(const float4*)(NTp + kc + col);
                v.x *= s.x; v.y *= s.y; v.z *= s.z; v.w *= s.w;
            }
            XT[col + 0][row] = v.x;
            XT[col + 1][row] = v.y;
            XT[col + 2][row] = v.z;
            XT[col + 3][row] = v.w;
        }
        __syncthreads();
#pragma unroll
        for (int kk = 0; kk < 32; ++kk) {
            float4 a4 = *(const float4*)(&XT[kk][rg * 4]);
            float4 w4 = *(const float4*)(Wc + kk * 64 + tx * 4);
            acc[0][0] = fmaf(a4.x, w4.x, acc[0][0]); acc[0][1] = fmaf(a4.x, w4.y, acc[0][1]);
            acc[0][2] = fmaf(a4.x, w4.z, acc[0][2]); acc[0][3] = fmaf(a4.x, w4.w, acc[0][3]);
            acc[1][0] = fmaf(a4.y, w4.x, acc[1][0]); acc[1][1] = fmaf(a4.y, w4.y, acc[1][1]);
            acc[1][2] = fmaf(a4.y, w4.z, acc[1][2]); acc[1][3] = fmaf(a4.y, w4.w, acc[1][3]);
            acc[2][0] = fmaf(a4.z, w4.x, acc[2][0]); acc[2][1] = fmaf(a4.z, w4.y, acc[2][1]);
            acc[2][2] = fmaf(a4.z, w4.z, acc[2][2]); acc[2][3] = fmaf(a4.z, w4.w, acc[2][3]);
            acc[3][0] = fmaf(a4.w, w4.x, acc[3][0]); acc[3][1] = fmaf(a4.w, w4.y, acc[3][1]);
            acc[3][2] = fmaf(a4.w, w4.z, acc[3][2]); acc[3][3] = fmaf(a4.w, w4.w, acc[3][3]);
        }
    }

    if (F) {
#pragma unroll
        for (int i = 0; i < 4; ++i) {
            size_t n = (size_t)r0 + rg * 4 + i;
            *(float4*)(F + n * 64 + tx * 4) =
                make_float4(acc[i][0], acc[i][1], acc[i][2], acc[i][3]);
        }
    }
    // el/er: thread's 4 cols belong to head tx>>2; reduce over the 4 lanes of
    // the head group (lane bits 0,1) via shfl_xor.
    if (EL) {
        float4 alv = ((const float4*)AL)[tx];
#pragma unroll
        for (int i = 0; i < 4; ++i) {
            float p = acc[i][0] * alv.x + acc[i][1] * alv.y +
                      acc[i][2] * alv.z + acc[i][3] * alv.w;
            p += __shfl_xor(p, 1, 64);
            p += __shfl_xor(p, 2, 64);
            if ((tx & 3) == 0) EL[((size_t)r0 + rg * 4 + i) * 4 + (tx >> 2)] = p;
        }
    }
    if (ER) {
        float4 arv = ((const float4*)AR)[tx];
#pragma unroll
        for (int i = 0; i < 4; ++i) {
            float p = acc[i][0] * arv.x + acc[i][1] * arv.y +
                      acc[i][2] * arv.z + acc[i][3] * arv.w;
            p += __shfl_xor(p, 1, 64);
            p += __shfl_xor(p, 2, 64);
            if ((tx & 3) == 0) ER[((size_t)r0 + rg * 4 + i) * 4 + (tx >> 2)] = p;
        }
    }
}

// ---------------- per-destination gather aggregation (no atomics) ----------
// HYBRID of R9/R10 (each measured):
//  phase 1 (R9 layout, lane=(edge j16, head g)): ONE exp + ONE el-gather per
//  lane per 16-edge chunk — minimal transcendental/gather count.
//  phase 2 (R10-style vector accumulate, lane=(col-group j16, edge-slot g)):
//  4 sub-iterations; per sub: 2 bpermute (sn + head weight) + 1 float4 fs
//  load + 4 fma. Per 16 edges: 8 shuffles + 4 vector loads (R9 needed 32+16;
//  R10 avoided shuffles but 4x'd the exps/gathers — both measured slower).
// Single-pass softmax (shift-invariant, |e|<~6 so exp can't overflow).
struct AggType { const int* row; const int* es; const float* el; const float* er; const float* fs; };
struct AggArgs { AggType t[3]; const float* b; float* op; float* oa; };

__device__ __forceinline__ float4 agg16v(const int* __restrict__ rowv, const int* __restrict__ es,
                                         const float* __restrict__ el, const float* __restrict__ er,
                                         const float* __restrict__ fs, int d, int lane,
                                         float* denOut) {
    float4 acc = make_float4(0.f, 0.f, 0.f, 0.f);
    float den = 0.f;
    int start = rowv[d], deg = rowv[d + 1] - start;
    if (deg > 0) {
        const int j16 = lane & 15;   // phase-1: edge slot | phase-2: col group (cols j16*4..+3)
        const int g   = lane >> 4;   // phase-1: head      | phase-2: edge sub-slot
        const int h   = j16 >> 2;    // phase-2: head owning this lane's cols
        const float rh = er[(size_t)d * 4 + g];
        for (int e0 = 0; e0 < deg; e0 += 16) {
            int o = e0 + j16;
            int sn = es[start + (o < deg ? o : 0)];
            float wv = 0.f;
            if (o < deg) wv = __expf(lrelu(el[(size_t)sn * 4 + g] + rh));
            den += wv;                                   // partial for (edge j16, head g)
#pragma unroll
            for (int sub = 0; sub < 4; ++sub) {
                int eidx = sub * 4 + g;                  // edge index within chunk, 0..15
                int snj  = __shfl(sn, eidx, 64);         // sn lives in lane (0..3)*16+eidx; take g=0
                float wj = __shfl(wv, (h << 4) + eidx, 64); // weight of (edge eidx, head h)
                float4 f4 = *(const float4*)(fs + (size_t)snj * 64 + j16 * 4);
                acc.x = fmaf(wj, f4.x, acc.x);
                acc.y = fmaf(wj, f4.y, acc.y);
                acc.z = fmaf(wj, f4.z, acc.z);
                acc.w = fmaf(wj, f4.w, acc.w);           // padded edges: wj=0, load harmless
            }
        }
    }
    *denOut = den;
    return acc;
}

__device__ __forceinline__ float4 agg_finish(float4 acc, float den, int lane) {
    // den: reduce over edge slots within each 16-lane head group -> den[g] per lane
#pragma unroll
    for (int w = 1; w < 16; w <<= 1) den += __shfl_xor(den, w, 64);
    // acc: reduce over the 4 edge sub-slots (lane>>4)
#pragma unroll
    for (int w = 16; w < 64; w <<= 1) {
        acc.x += __shfl_xor(acc.x, w, 64);
        acc.y += __shfl_xor(acc.y, w, 64);
        acc.z += __shfl_xor(acc.z, w, 64);
        acc.w += __shfl_xor(acc.w, w, 64);
    }
    // fetch den for the head of this lane's columns (source lane h*16 holds den[h])
    float denh = __shfl(den, (((lane & 15) >> 2) << 4), 64);
    float inv = 1.f / fmaxf(denh, 1e-9f);
    acc.x *= inv; acc.y *= inv; acc.z *= inv; acc.w *= inv;
    return acc;
}

__global__ __launch_bounds__(256) void k_agg(AggArgs A) {
    int wid = (blockIdx.x * 256 + threadIdx.x) >> 6;  // one wave per dst node
    int lane = threadIdx.x & 63;
    int c16 = lane & 15;
    if (wid < N_P) {
        float d0, d1;
        float4 a0 = agg16v(A.t[0].row, A.t[0].es, A.t[0].el, A.t[0].er, A.t[0].fs, wid, lane, &d0);
        float4 a1 = agg16v(A.t[1].row, A.t[1].es, A.t[1].el, A.t[1].er, A.t[1].fs, wid, lane, &d1);
        a0 = agg_finish(a0, d0, lane);
        a1 = agg_finish(a1, d1, lane);
        if (lane < 16) {
            float4 b0 = *(const float4*)(A.b + c16 * 4);
            float4 b1 = *(const float4*)(A.b + 64 + c16 * 4);
            float4 o = make_float4(a0.x + a1.x + b0.x + b1.x,
                                   a0.y + a1.y + b0.y + b1.y,
                                   a0.z + a1.z + b0.z + b1.z,
                                   a0.w + a1.w + b0.w + b1.w);
            *(float4*)(A.op + (size_t)wid * 64 + c16 * 4) = o;
        }
    } else {
        int d = wid - N_P;
        float d2;
        float4 a2 = agg16v(A.t[2].row, A.t[2].es, A.t[2].el, A.t[2].er, A.t[2].fs, d, lane, &d2);
        a2 = agg_finish(a2, d2, lane);
        if (lane < 16) {
            float4 b2 = *(const float4*)(A.b + 128 + c16 * 4);
            float4 o = make_float4(a2.x + b2.x, a2.y + b2.y, a2.z + b2.z, a2.w + b2.w);
            *(float4*)(A.oa + (size_t)d * 64 + c16 * 4) = o;
        }
    }
}

// ---------------- hf build: h2 = h1 + C, row l2-normalize, concat ------------
__global__ __launch_bounds__(256) void k_hf(const float* __restrict__ h1, float* __restrict__ hf,
                                            const float* __restrict__ ln1gb,
                                            const float* __restrict__ aw, const float* __restrict__ ab,
                                            const float* __restrict__ ln2gb,
                                            const float* __restrict__ fw1, const float* __restrict__ fb1,
                                            const float* __restrict__ fw2, const float* __restrict__ fb2) {
    __shared__ float Cs;
    if (threadIdx.x == 0) {
        // LN over size-1 axis -> exactly its bias term
        float y1 = ln1gb[1];
        float v  = y1 * aw[2] + ab[2];          // v constant; softmax uniform -> o = v
        float o  = v * aw[3] + ab[3];
        float y2 = ln2gb[1];
        float f  = fb2[0];
#pragma unroll
        for (int q = 0; q < 16; ++q) {
            float zz = y2 * fw1[q] + fb1[q];
            f += 0.5f * zz * (1.f + erff(zz * 0.70710678118654752f)) * fw2[q];
        }
        Cs = o + f;
    }
    __syncthreads();
    float C = Cs;
    int lane = threadIdx.x & 63;
    int row  = blockIdx.x * 4 + (threadIdx.x >> 6);
    float v1 = h1[(size_t)row * 64 + lane];
    float s1 = v1 * v1;
#pragma unroll
    for (int w = 1; w < 64; w <<= 1) s1 += __shfl_xor(s1, w, 64);
    float o1 = v1 / fmaxf(sqrtf(s1), 1e-12f);
    float v2 = v1 + C;
    float s2 = v2 * v2;
#pragma unroll
    for (int w = 1; w < 64; w <<= 1) s2 += __shfl_xor(s2, w, 64);
    float o2 = v2 / fmaxf(sqrtf(s2), 1e-12f);
    hf[(size_t)row * 128 + lane]      = o1;
    hf[(size_t)row * 128 + 64 + lane] = o2;
}

// ---------------- final GEMM: out = hf(16384x128) @ linW(128x349) + linb -----
__global__ __launch_bounds__(256) void k_gemm_out(const float* __restrict__ X,
                                                  const float* __restrict__ W,
                                                  const float* __restrict__ bias,
                                                  float* __restrict__ out) {
    __shared__ float Wc[32 * 64];
    __shared__ float XT[32][68];
    const int tid = threadIdx.x;
    const int tx  = tid & 15;
    const int rg  = tid >> 4;
    const int r0  = blockIdx.x * 64;
    const int c0  = blockIdx.y * 64;

    float acc[4][4] = {};

    for (int kc = 0; kc < 128; kc += 32) {
        __syncthreads();
#pragma unroll
        for (int it = 0; it < 2; ++it) {
            int idx = tid * 4 + it * 1024;
            int k = idx >> 6, c = idx & 63;
            int gk = kc + k;
            float4 v;
            int gc = c0 + c;
            v.x = (gc + 0 < OUTD) ? W[(size_t)gk * OUTD + gc + 0] : 0.f;
            v.y = (gc + 1 < OUTD) ? W[(size_t)gk * OUTD + gc + 1] : 0.f;
            v.z = (gc + 2 < OUTD) ? W[(size_t)gk * OUTD + gc + 2] : 0.f;
            v.w = (gc + 3 < OUTD) ? W[(size_t)gk * OUTD + gc + 3] : 0.f;
            *(float4*)(Wc + idx) = v;
        }
#pragma unroll
        for (int it = 0; it < 2; ++it) {
            int idx = tid * 4 + it * 1024;
            int row = idx >> 5, col = idx & 31;
            float4 v = *(const float4*)(X + (size_t)(r0 + row) * 128 + kc + col);
            XT[col + 0][row] = v.x;
            XT[col + 1][row] = v.y;
            XT[col + 2][row] = v.z;
            XT[col + 3][row] = v.w;
        }
        __syncthreads();
#pragma unroll
        for (int kk = 0; kk < 32; ++kk) {
            float4 a4 = *(const float4*)(&XT[kk][rg * 4]);
            float4 w4 = *(const float4*)(Wc + kk * 64 + tx * 4);
            acc[0][0] = fmaf(a4.x, w4.x, acc[0][0]); acc[0][1] = fmaf(a4.x, w4.y, acc[0][1]);
            acc[0][2] = fmaf(a4.x, w4.z, acc[0][2]); acc[0][3] = fmaf(a4.x, w4.w, acc[0][3]);
            acc[1][0] = fmaf(a4.y, w4.x, acc[1][0]); acc[1][1] = fmaf(a4.y, w4.y, acc[1][1]);
            acc[1][2] = fmaf(a4.y, w4.z, acc[1][2]); acc[1][3] = fmaf(a4.y, w4.w, acc[1][3]);
            acc[2][0] = fmaf(a4.z, w4.x, acc[2][0]); acc[2][1] = fmaf(a4.z, w4.y, acc[2][1]);
            acc[2][2] = fmaf(a4.z, w4.z, acc[2][2]); acc[2][3] = fmaf(a4.z, w4.w, acc[2][3]);
            acc[3][0] = fmaf(a4.w, w4.x, acc[3][0]); acc[3][1] = fmaf(a4.w, w4.y, acc[3][1]);
            acc[3][2] = fmaf(a4.w, w4.z, acc[3][2]); acc[3][3] = fmaf(a4.w, w4.w, acc[3][3]);
        }
    }

    float b4[4];
#pragma unroll
    for (int q = 0; q < 4; ++q) {
        int c = c0 + tx * 4 + q;
        b4[q] = (c < OUTD) ? bias[c] : 0.f;
    }
#pragma unroll
    for (int i = 0; i < 4; ++i) {
        size_t n = (size_t)r0 + rg * 4 + i;
#pragma unroll
        for (int q = 0; q < 4; ++q) {
            int c = c0 + tx * 4 + q;
            if (c < OUTD) out[n * OUTD + c] = acc[i][q] + b4[q];
        }
    }
}

// ---------------- host ----------------
extern "C" void kernel_launch(void* const* d_in, const int* in_sizes, int n_in,
                              void* d_out, int out_size, void* d_ws, size_t ws_size,
                              hipStream_t stream) {
    const float* x_author = (const float*)d_in[0];
    const float* x_paper  = (const float*)d_in[1];
    const float* ntype    = (const float*)d_in[2];
    const float* W0  = (const float*)d_in[3];
    const float* al0 = (const float*)d_in[4];
    const float* ar0 = (const float*)d_in[5];
    const float* b0  = (const float*)d_in[6];
    const float* W1  = (const float*)d_in[7];
    const float* al1 = (const float*)d_in[8];
    const float* ar1 = (const float*)d_in[9];
    const float* b1  = (const float*)d_in[10];
    const float* ln1gb = (const float*)d_in[11];
    const float* attw  = (const float*)d_in[12];
    const float* attb  = (const float*)d_in[13];
    const float* ln2gb = (const float*)d_in[14];
    const float* fw1 = (const float*)d_in[15];
    const float* fb1 = (const float*)d_in[16];
    const float* fw2 = (const float*)d_in[17];
    const float* fb2 = (const float*)d_in[18];
    const float* linW = (const float*)d_in[19];
    const float* linb = (const float*)d_in[20];
    const int* srcW = (const int*)d_in[21];
    const int* dstW = (const int*)d_in[22];
    const int* srcC = (const int*)d_in[23];
    const int* dstC = (const int*)d_in[24];
    const int* srcR = (const int*)d_in[25];
    const int* dstR = (const int*)d_in[26];
    float* out = (float*)d_out;

    // ---- workspace carve-up ----
    float* ws = (float*)d_ws;
    size_t off = 0;
    float* fsW = ws + off; off += (size_t)N_A * HID;
    float* fsC = ws + off; off += (size_t)N_P * HID;
    float* fsR = ws + off; off += (size_t)N_P * HID;
    float* elw = ws + off; off += (size_t)N_A * NH;
    float* erw = ws + off; off += (size_t)N_P * NH;
    float* elc = ws + off; off += (size_t)N_P * NH;
    float* erc = ws + off; off += (size_t)N_P * NH;
    float* elr = ws + off; off += (size_t)N_P * NH;
    float* err = ws + off; off += (size_t)N_A * NH;
    float* oa0 = ws + off; off += (size_t)N_A * HID;
    float* op0 = ws + off; off += (size_t)N_P * HID;
    float* oa1 = ws + off; off += (size_t)N_A * HID;
    float* op1 = ws + off; off += (size_t)N_P * HID;
    float* hf  = ws + off; off += (size_t)N_P * 2 * HID;
    int* ccnt  = (int*)(ws + off); off += 3 * NB * 256;
    int* coffs = (int*)(ws + off); off += 3 * NB * 256;
    int* crow  = (int*)(ws + off); off += 3 * 257 + 1;
    int* row   = (int*)(ws + off); off += 3 * 16385 + 1;
    int* ebW  = (int*)(ws + off); off += NE;
    int* ebC  = (int*)(ws + off); off += NE;
    int* ebR  = (int*)(ws + off); off += NE;
    int* esW  = (int*)(ws + off); off += NE;
    int* esC  = (int*)(ws + off); off += NE;
    int* esR  = (int*)(ws + off); off += NE;

    const int* rowW = row;
    const int* rowC = row + 16385;
    const int* rowR = row + 2 * 16385;

    const float* ntA = ntype;            // author scale row (128)
    const float* ntP = ntype + IN_D;     // paper scale row

    // ---- layer job tables (layer 0 reads raw x, scaled by NT on load) ----
    GemmJobs j0{};
    j0.X[0] = x_author; j0.W[0] = W0;                  j0.NT[0] = ntA;
    j0.F[0] = fsW; j0.EL[0] = elw; j0.ER[0] = nullptr; j0.AL[0] = al0;       j0.AR[0] = nullptr;
    j0.X[1] = x_paper;  j0.W[1] = W0;                  j0.NT[1] = ntP;
    j0.F[1] = nullptr; j0.EL[1] = nullptr; j0.ER[1] = erw; j0.AL[1] = nullptr; j0.AR[1] = ar0;
    j0.X[2] = x_paper;  j0.W[2] = W0 + IN_D * HID;     j0.NT[2] = ntP;
    j0.F[2] = fsC; j0.EL[2] = elc; j0.ER[2] = erc;     j0.AL[2] = al0 + 64;  j0.AR[2] = ar0 + 64;
    j0.X[3] = x_paper;  j0.W[3] = W0 + 2 * IN_D * HID; j0.NT[3] = ntP;
    j0.F[3] = fsR; j0.EL[3] = elr; j0.ER[3] = nullptr; j0.AL[3] = al0 + 128; j0.AR[3] = nullptr;
    j0.X[4] = x_author; j0.W[4] = W0 + 2 * IN_D * HID; j0.NT[4] = ntA;
    j0.F[4] = nullptr; j0.EL[4] = nullptr; j0.ER[4] = err; j0.AL[4] = nullptr; j0.AR[4] = ar0 + 128;

    GemmJobs j1{};
    j1.X[0] = oa0; j1.W[0] = W1;                   j1.NT[0] = nullptr;
    j1.F[0] = fsW; j1.EL[0] = elw; j1.ER[0] = nullptr; j1.AL[0] = al1;       j1.AR[0] = nullptr;
    j1.X[1] = op0; j1.W[1] = W1;                   j1.NT[1] = nullptr;
    j1.F[1] = nullptr; j1.EL[1] = nullptr; j1.ER[1] = erw; j1.AL[1] = nullptr; j1.AR[1] = ar1;
    j1.X[2] = op0; j1.W[2] = W1 + HID * HID;       j1.NT[2] = nullptr;
    j1.F[2] = fsC; j1.EL[2] = elc; j1.ER[2] = erc;     j1.AL[2] = al1 + 64;  j1.AR[2] = ar1 + 64;
    j1.X[3] = op0; j1.W[3] = W1 + 2 * HID * HID;   j1.NT[3] = nullptr;
    j1.F[3] = fsR; j1.EL[3] = elr; j1.ER[3] = nullptr; j1.AL[3] = al1 + 128; j1.AR[3] = nullptr;
    j1.X[4] = oa0; j1.W[4] = W1 + 2 * HID * HID;   j1.NT[4] = nullptr;
    j1.F[4] = nullptr; j1.EL[4] = nullptr; j1.ER[4] = err; j1.AL[4] = nullptr; j1.AR[4] = ar1 + 128;

    AggArgs a0{};
    a0.t[0] = {rowW, esW, elw, erw, fsW};
    a0.t[1] = {rowC, esC, elc, erc, fsC};
    a0.t[2] = {rowR, esR, elr, err, fsR};
    a0.b = b0; a0.op = op0; a0.oa = oa0;
    AggArgs a1 = a0;
    a1.b = b1; a1.op = op1; a1.oa = oa1;

    // ---- launches ----
    // CSR build (edge lists constant across layers): two-level partition
    k_chist<<<dim3(NB, 3), 256, 0, stream>>>(dstW, dstC, dstR, ccnt);
    k_coffs<<<1, 768, 0, stream>>>(ccnt, coffs, crow);
    k_cscatter<<<dim3(NB, 3), 256, 0, stream>>>(srcW, dstW, srcC, dstC, srcR, dstR,
                                                coffs, ebW, ebC, ebR);
    k_fine<<<dim3(256, 3), 256, 0, stream>>>(crow, ebW, ebC, ebR, row, esW, esC, esR);

    // layer 0 (ntype scale folded into X load)
    k_gemm<IN_D, 0><<<dim3(N_A / 64, 1, 5), 256, 0, stream>>>(j0);
    k_agg<<<(N_P + N_A) / 4, 256, 0, stream>>>(a0);

    // layer 1 (relu folded into GEMM X loads)
    k_gemm<HID, 1><<<dim3(N_A / 64, 1, 5), 256, 0, stream>>>(j1);
    k_agg<<<(N_P + N_A) / 4, 256, 0, stream>>>(a1);

    // epilogue
    k_hf<<<N_P / 4, 256, 0, stream>>>(op1, hf, ln1gb, attw, attb, ln2gb, fw1, fb1, fw2, fb2);
    k_gemm_out<<<dim3(N_P / 64, (OUTD + 63) / 64), 256, 0, stream>>>(hf, linW, linb, out);
}

// Round 12
// 148.827 us; speedup vs baseline: 1.2386x; 1.0758x over previous
//
#include <hip/hip_runtime.h>
#include <math.h>

// ---------------- problem constants ----------------
constexpr int N_A   = 16384;
constexpr int N_P   = 16384;
constexpr int IN_D  = 128;
constexpr int HID   = 64;
constexpr int NH    = 4;    // heads
constexpr int OUTD  = 349;
constexpr int NE    = 262144; // edges per type (2^18)
constexpr int NB    = 64;     // coarse-partition blocks per type (4096 edges each)
constexpr float NEG = 0.2f;

__device__ __forceinline__ float lrelu(float x) { return x > 0.f ? x : NEG * x; }

// ---------------- CSR build: two-level coherent partition ----------------
__global__ __launch_bounds__(256) void k_chist(const int* __restrict__ dW, const int* __restrict__ dC,
                                               const int* __restrict__ dR, int* __restrict__ ccnt) {
    __shared__ int h[256];
    const int t = blockIdx.y;
    const int* __restrict__ d = t == 0 ? dW : t == 1 ? dC : dR;
    const int tid = threadIdx.x;
    h[tid] = 0;
    __syncthreads();
    const int base = blockIdx.x * 4096;
#pragma unroll
    for (int i = 0; i < 16; ++i) {
        int dst = d[base + i * 256 + tid];
        atomicAdd(&h[dst >> 6], 1);
    }
    __syncthreads();
    ccnt[(t * NB + blockIdx.x) * 256 + tid] = h[tid];
}

__global__ __launch_bounds__(768) void k_coffs(const int* __restrict__ ccnt, int* __restrict__ coffs,
                                               int* __restrict__ crow) {
    const int tid = threadIdx.x;
    const int t = tid >> 8, bin = tid & 255;
    int total = 0;
    for (int b = 0; b < NB; ++b) total += ccnt[(t * NB + b) * 256 + bin];
    __shared__ int sc[768];
    sc[tid] = total;
    __syncthreads();
    for (int w = 1; w < 256; w <<= 1) {
        int v = (bin >= w) ? sc[tid - w] : 0;
        __syncthreads();
        sc[tid] += v;
        __syncthreads();
    }
    const int incl = sc[tid];
    const int base = incl - total;       // exclusive prefix within type
    crow[t * 257 + bin] = base;
    if (bin == 255) crow[t * 257 + 256] = incl;   // == NE
    int run = base;
    for (int b = 0; b < NB; ++b) {
        int c = ccnt[(t * NB + b) * 256 + bin];
        coffs[(t * NB + b) * 256 + bin] = run;
        run += c;
    }
}

__global__ __launch_bounds__(256) void k_cscatter(const int* __restrict__ sW, const int* __restrict__ dW,
                                                  const int* __restrict__ sC, const int* __restrict__ dC,
                                                  const int* __restrict__ sR, const int* __restrict__ dR,
                                                  const int* __restrict__ coffs,
                                                  int* __restrict__ ebW, int* __restrict__ ebC,
                                                  int* __restrict__ ebR) {
    __shared__ int cur[256];
    const int t = blockIdx.y;
    const int* __restrict__ sp = t == 0 ? sW : t == 1 ? sC : sR;
    const int* __restrict__ dp = t == 0 ? dW : t == 1 ? dC : dR;
    int* __restrict__ eb = t == 0 ? ebW : t == 1 ? ebC : ebR;
    const int tid = threadIdx.x;
    cur[tid] = coffs[(t * NB + blockIdx.x) * 256 + tid];
    __syncthreads();
    const int base = blockIdx.x * 4096;
#pragma unroll
    for (int i = 0; i < 16; ++i) {
        int e = base + i * 256 + tid;
        int dst = dp[e], src = sp[e];
        int pos = atomicAdd(&cur[dst >> 6], 1);
        eb[pos] = src | ((dst & 63) << 14);
    }
}

__global__ __launch_bounds__(256) void k_fine(const int* __restrict__ crow,
                                              const int* __restrict__ ebW, const int* __restrict__ ebC,
                                              const int* __restrict__ ebR,
                                              int* __restrict__ row,
                                              int* __restrict__ esW, int* __restrict__ esC,
                                              int* __restrict__ esR) {
    __shared__ int bins[64], exc[64], cur[64];
    const int t = blockIdx.y, cb = blockIdx.x, tid = threadIdx.x;
    const int* __restrict__ eb = t == 0 ? ebW : t == 1 ? ebC : ebR;
    int* __restrict__ es = t == 0 ? esW : t == 1 ? esC : esR;
    const int lo = crow[t * 257 + cb], hi = crow[t * 257 + cb + 1];
    if (tid < 64) bins[tid] = 0;
    __syncthreads();
    for (int e = lo + tid; e < hi; e += 256) atomicAdd(&bins[eb[e] >> 14], 1);
    __syncthreads();
    if (tid == 0) {
        int r = 0;
#pragma unroll
        for (int j = 0; j < 64; ++j) { exc[j] = r; cur[j] = r; r += bins[j]; }
    }
    __syncthreads();
    if (tid < 64) row[t * 16385 + cb * 64 + tid] = lo + exc[tid];
    if (tid == 0 && cb == 255) row[t * 16385 + 16384] = crow[t * 257 + 256];
    for (int e = lo + tid; e < hi; e += 256) {
        int v = eb[e];
        int pos = atomicAdd(&cur[v >> 14], 1);
        es[lo + pos] = v & 16383;
    }
}

// ---------------- batched GEMM (X@W) + el/er head reductions -------
struct GemmJobs {
    const float* X[5];  const float* W[5];  const float* NT[5];
    float* F[5];        float* EL[5];       float* ER[5];
    const float* AL[5]; const float* AR[5];
};

template <int K, int RELU>
__global__ __launch_bounds__(256) void k_gemm(GemmJobs j) {
    __shared__ float Wc[32 * 64];
    __shared__ float XT[32][68];

    const float* __restrict__ X;  const float* __restrict__ Wp;  const float* __restrict__ NTp;
    float* __restrict__ F;  float* __restrict__ EL;  float* __restrict__ ER;
    const float* __restrict__ AL; const float* __restrict__ AR;
    switch (blockIdx.z) {                         // block-uniform, static indices
      case 0: X=j.X[0]; Wp=j.W[0]; NTp=j.NT[0]; F=j.F[0]; EL=j.EL[0]; ER=j.ER[0]; AL=j.AL[0]; AR=j.AR[0]; break;
      case 1: X=j.X[1]; Wp=j.W[1]; NTp=j.NT[1]; F=j.F[1]; EL=j.EL[1]; ER=j.ER[1]; AL=j.AL[1]; AR=j.AR[1]; break;
      case 2: X=j.X[2]; Wp=j.W[2]; NTp=j.NT[2]; F=j.F[2]; EL=j.EL[2]; ER=j.ER[2]; AL=j.AL[2]; AR=j.AR[2]; break;
      case 3: X=j.X[3]; Wp=j.W[3]; NTp=j.NT[3]; F=j.F[3]; EL=j.EL[3]; ER=j.ER[3]; AL=j.AL[3]; AR=j.AR[3]; break;
      default: X=j.X[4]; Wp=j.W[4]; NTp=j.NT[4]; F=j.F[4]; EL=j.EL[4]; ER=j.ER[4]; AL=j.AL[4]; AR=j.AR[4]; break;
    }

    const int tid = threadIdx.x;
    const int tx  = tid & 15;     // col group: cols tx*4..tx*4+3
    const int rg  = tid >> 4;     // row group: rows rg*4..rg*4+3
    const int r0  = blockIdx.x * 64;

    float acc[4][4] = {};

    for (int kc = 0; kc < K; kc += 32) {
        __syncthreads();
        // stage W chunk (32x64)
#pragma unroll
        for (int it = 0; it < 2; ++it) {
            int idx = tid * 4 + it * 1024;
            int k = idx >> 6, c = idx & 63;
            *(float4*)(Wc + idx) = *(const float4*)(Wp + (size_t)(kc + k) * 64 + c);
        }
        // stage X chunk transposed (XT[k][row])
#pragma unroll
        for (int it = 0; it < 2; ++it) {
            int idx = tid * 4 + it * 1024;
            int row = idx >> 5, col = idx & 31;
            float4 v = *(const float4*)(X + (size_t)(r0 + row) * K + kc + col);
            if (RELU) {
                v.x = fmaxf(v.x, 0.f); v.y = fmaxf(v.y, 0.f);
                v.z = fmaxf(v.z, 0.f); v.w = fmaxf(v.w, 0.f);
            }
            if (NTp) {
                float4 s = *(const float4*)(NTp + kc + col);
                v.x *= s.x; v.y *= s.y; v.z *= s.z; v.w *= s.w;
            }
            XT[col + 0][row] = v.x;
            XT[col + 1][row] = v.y;
            XT[col + 2][row] = v.z;
            XT[col + 3][row] = v.w;
        }
        __syncthreads();
#pragma unroll
        for (int kk = 0; kk < 32; ++kk) {
            float4 a4 = *(const float4*)(&XT[kk][rg * 4]);
            float4 w4 = *(const float4*)(Wc + kk * 64 + tx * 4);
            acc[0][0] = fmaf(a4.x, w4.x, acc[0][0]); acc[0][1] = fmaf(a4.x, w4.y, acc[0][1]);
            acc[0][2] = fmaf(a4.x, w4.z, acc[0][2]); acc[0][3] = fmaf(a4.x, w4.w, acc[0][3]);
            acc[1][0] = fmaf(a4.y, w4.x, acc[1][0]); acc[1][1] = fmaf(a4.y, w4.y, acc[1][1]);
            acc[1][2] = fmaf(a4.y, w4.z, acc[1][2]); acc[1][3] = fmaf(a4.y, w4.w, acc[1][3]);
            acc[2][0] = fmaf(a4.z, w4.x, acc[2][0]); acc[2][1] = fmaf(a4.z, w4.y, acc[2][1]);
            acc[2][2] = fmaf(a4.z, w4.z, acc[2][2]); acc[2][3] = fmaf(a4.z, w4.w, acc[2][3]);
            acc[3][0] = fmaf(a4.w, w4.x, acc[3][0]); acc[3][1] = fmaf(a4.w, w4.y, acc[3][1]);
            acc[3][2] = fmaf(a4.w, w4.z, acc[3][2]); acc[3][3] = fmaf(a4.w, w4.w, acc[3][3]);
        }
    }

    if (F) {
#pragma unroll
        for (int i = 0; i < 4; ++i) {
            size_t n = (size_t)r0 + rg * 4 + i;
            *(float4*)(F + n * 64 + tx * 4) =
                make_float4(acc[i][0], acc[i][1], acc[i][2], acc[i][3]);
        }
    }
    if (EL) {
        float4 alv = ((const float4*)AL)[tx];
#pragma unroll
        for (int i = 0; i < 4; ++i) {
            float p = acc[i][0] * alv.x + acc[i][1] * alv.y +
                      acc[i][2] * alv.z + acc[i][3] * alv.w;
            p += __shfl_xor(p, 1, 64);
            p += __shfl_xor(p, 2, 64);
            if ((tx & 3) == 0) EL[((size_t)r0 + rg * 4 + i) * 4 + (tx >> 2)] = p;
        }
    }
    if (ER) {
        float4 arv = ((const float4*)AR)[tx];
#pragma unroll
        for (int i = 0; i < 4; ++i) {
            float p = acc[i][0] * arv.x + acc[i][1] * arv.y +
                      acc[i][2] * arv.z + acc[i][3] * arv.w;
            p += __shfl_xor(p, 1, 64);
            p += __shfl_xor(p, 2, 64);
            if ((tx & 3) == 0) ER[((size_t)r0 + rg * 4 + i) * 4 + (tx >> 2)] = p;
        }
    }
}

// ---------------- per-destination gather aggregation (no atomics) ----------
// R11 hybrid (measured best): phase 1 lane=(edge j16, head g) — one exp + one
// el-gather per lane per 16-edge chunk; phase 2 lane=(col-group j16, slot g) —
// 4 subs of {2 bpermute + float4 fs load + 4 fma}. Single-pass softmax.
// LAYER-1 NOTE: the reference's second-layer author output (revw GAT) is DEAD
// (h1 = hp only), so k_agg<1> runs paper waves only AND fuses the k_hf
// epilogue: all 64 lanes hold the full output row after agg_finish, so the
// wave computes both l2 norms + the scalar transformer constant C in-register
// and writes hf directly (no op1 round-trip, no k_hf kernel).
struct AggType { const int* row; const int* es; const float* el; const float* er; const float* fs; };
struct AggArgs {
    AggType t[3]; const float* b; float* op; float* oa;
    // layer-1 fused-hf extras:
    float* hf;
    const float* ln1gb; const float* aw; const float* ab; const float* ln2gb;
    const float* fw1; const float* fb1; const float* fw2; const float* fb2;
};

__device__ __forceinline__ float4 agg16v(const int* __restrict__ rowv, const int* __restrict__ es,
                                         const float* __restrict__ el, const float* __restrict__ er,
                                         const float* __restrict__ fs, int d, int lane,
                                         float* denOut) {
    float4 acc = make_float4(0.f, 0.f, 0.f, 0.f);
    float den = 0.f;
    int start = rowv[d], deg = rowv[d + 1] - start;
    if (deg > 0) {
        const int j16 = lane & 15;   // phase-1: edge slot | phase-2: col group (cols j16*4..+3)
        const int g   = lane >> 4;   // phase-1: head      | phase-2: edge sub-slot
        const int h   = j16 >> 2;    // phase-2: head owning this lane's cols
        const float rh = er[(size_t)d * 4 + g];
        for (int e0 = 0; e0 < deg; e0 += 16) {
            int o = e0 + j16;
            int sn = es[start + (o < deg ? o : 0)];
            float wv = 0.f;
            if (o < deg) wv = __expf(lrelu(el[(size_t)sn * 4 + g] + rh));
            den += wv;                                   // partial for (edge j16, head g)
#pragma unroll
            for (int sub = 0; sub < 4; ++sub) {
                int eidx = sub * 4 + g;                  // edge index within chunk, 0..15
                int snj  = __shfl(sn, eidx, 64);         // sn of edge eidx (from g=0 lanes)
                float wj = __shfl(wv, (h << 4) + eidx, 64); // weight of (edge eidx, head h)
                float4 f4 = *(const float4*)(fs + (size_t)snj * 64 + j16 * 4);
                acc.x = fmaf(wj, f4.x, acc.x);
                acc.y = fmaf(wj, f4.y, acc.y);
                acc.z = fmaf(wj, f4.z, acc.z);
                acc.w = fmaf(wj, f4.w, acc.w);           // padded edges: wj=0, load harmless
            }
        }
    }
    *denOut = den;
    return acc;
}

__device__ __forceinline__ float4 agg_finish(float4 acc, float den, int lane) {
#pragma unroll
    for (int w = 1; w < 16; w <<= 1) den += __shfl_xor(den, w, 64);
#pragma unroll
    for (int w = 16; w < 64; w <<= 1) {
        acc.x += __shfl_xor(acc.x, w, 64);
        acc.y += __shfl_xor(acc.y, w, 64);
        acc.z += __shfl_xor(acc.z, w, 64);
        acc.w += __shfl_xor(acc.w, w, 64);
    }
    float denh = __shfl(den, (((lane & 15) >> 2) << 4), 64);
    float inv = 1.f / fmaxf(denh, 1e-9f);
    acc.x *= inv; acc.y *= inv; acc.z *= inv; acc.w *= inv;
    return acc;
}

template <int L1>
__global__ __launch_bounds__(256) void k_agg(AggArgs A) {
    int wid = (blockIdx.x * 256 + threadIdx.x) >> 6;  // one wave per dst node
    int lane = threadIdx.x & 63;
    int c16 = lane & 15;
    if (L1 == 0) {
        if (wid < N_P) {
            float d0, d1;
            float4 a0 = agg16v(A.t[0].row, A.t[0].es, A.t[0].el, A.t[0].er, A.t[0].fs, wid, lane, &d0);
            float4 a1 = agg16v(A.t[1].row, A.t[1].es, A.t[1].el, A.t[1].er, A.t[1].fs, wid, lane, &d1);
            a0 = agg_finish(a0, d0, lane);
            a1 = agg_finish(a1, d1, lane);
            if (lane < 16) {
                float4 b0 = *(const float4*)(A.b + c16 * 4);
                float4 b1 = *(const float4*)(A.b + 64 + c16 * 4);
                float4 o = make_float4(a0.x + a1.x + b0.x + b1.x,
                                       a0.y + a1.y + b0.y + b1.y,
                                       a0.z + a1.z + b0.z + b1.z,
                                       a0.w + a1.w + b0.w + b1.w);
                *(float4*)(A.op + (size_t)wid * 64 + c16 * 4) = o;
            }
        } else {
            int d = wid - N_P;
            float d2;
            float4 a2 = agg16v(A.t[2].row, A.t[2].es, A.t[2].el, A.t[2].er, A.t[2].fs, d, lane, &d2);
            a2 = agg_finish(a2, d2, lane);
            if (lane < 16) {
                float4 b2 = *(const float4*)(A.b + 128 + c16 * 4);
                float4 o = make_float4(a2.x + b2.x, a2.y + b2.y, a2.z + b2.z, a2.w + b2.w);
                *(float4*)(A.oa + (size_t)d * 64 + c16 * 4) = o;
            }
        }
    } else {
        // paper waves only (author output of layer 1 is dead)
        float d0, d1;
        float4 a0 = agg16v(A.t[0].row, A.t[0].es, A.t[0].el, A.t[0].er, A.t[0].fs, wid, lane, &d0);
        float4 a1 = agg16v(A.t[1].row, A.t[1].es, A.t[1].el, A.t[1].er, A.t[1].fs, wid, lane, &d1);
        a0 = agg_finish(a0, d0, lane);
        a1 = agg_finish(a1, d1, lane);
        float4 b0 = *(const float4*)(A.b + c16 * 4);
        float4 b1 = *(const float4*)(A.b + 64 + c16 * 4);
        float4 o = make_float4(a0.x + a1.x + b0.x + b1.x,
                               a0.y + a1.y + b0.y + b1.y,
                               a0.z + a1.z + b0.z + b1.z,
                               a0.w + a1.w + b0.w + b1.w);
        // transformer-block constant C (LN over size-1 axis degenerates to bias)
        float y1 = A.ln1gb[1];
        float vv = y1 * A.aw[2] + A.ab[2];
        float oo = vv * A.aw[3] + A.ab[3];
        float y2 = A.ln2gb[1];
        float f  = A.fb2[0];
#pragma unroll
        for (int q = 0; q < 16; ++q) {
            float zz = y2 * A.fw1[q] + A.fb1[q];
            f += 0.5f * zz * (1.f + erff(zz * 0.70710678118654752f)) * A.fw2[q];
        }
        float C = oo + f;
        float4 oc = make_float4(o.x + C, o.y + C, o.z + C, o.w + C);
        // l2 norms over the 64-col row (held across each 16-lane group)
        float s1 = o.x * o.x + o.y * o.y + o.z * o.z + o.w * o.w;
        float s2 = oc.x * oc.x + oc.y * oc.y + oc.z * oc.z + oc.w * oc.w;
#pragma unroll
        for (int w = 1; w < 16; w <<= 1) {
            s1 += __shfl_xor(s1, w, 64);
            s2 += __shfl_xor(s2, w, 64);
        }
        float i1 = 1.f / fmaxf(sqrtf(s1), 1e-12f);
        float i2 = 1.f / fmaxf(sqrtf(s2), 1e-12f);
        if (lane < 16) {
            *(float4*)(A.hf + (size_t)wid * 128 + c16 * 4) =
                make_float4(o.x * i1, o.y * i1, o.z * i1, o.w * i1);
            *(float4*)(A.hf + (size_t)wid * 128 + 64 + c16 * 4) =
                make_float4(oc.x * i2, oc.y * i2, oc.z * i2, oc.w * i2);
        }
    }
}

// ---------------- final GEMM: out = hf(16384x128) @ linW(128x349) + linb -----
__global__ __launch_bounds__(256) void k_gemm_out(const float* __restrict__ X,
                                                  const float* __restrict__ W,
                                                  const float* __restrict__ bias,
                                                  float* __restrict__ out) {
    __shared__ float Wc[32 * 64];
    __shared__ float XT[32][68];
    const int tid = threadIdx.x;
    const int tx  = tid & 15;
    const int rg  = tid >> 4;
    const int r0  = blockIdx.x * 64;
    const int c0  = blockIdx.y * 64;

    float acc[4][4] = {};

    for (int kc = 0; kc < 128; kc += 32) {
        __syncthreads();
#pragma unroll
        for (int it = 0; it < 2; ++it) {
            int idx = tid * 4 + it * 1024;
            int k = idx >> 6, c = idx & 63;
            int gk = kc + k;
            float4 v;
            int gc = c0 + c;
            v.x = (gc + 0 < OUTD) ? W[(size_t)gk * OUTD + gc + 0] : 0.f;
            v.y = (gc + 1 < OUTD) ? W[(size_t)gk * OUTD + gc + 1] : 0.f;
            v.z = (gc + 2 < OUTD) ? W[(size_t)gk * OUTD + gc + 2] : 0.f;
            v.w = (gc + 3 < OUTD) ? W[(size_t)gk * OUTD + gc + 3] : 0.f;
            *(float4*)(Wc + idx) = v;
        }
#pragma unroll
        for (int it = 0; it < 2; ++it) {
            int idx = tid * 4 + it * 1024;
            int row = idx >> 5, col = idx & 31;
            float4 v = *(const float4*)(X + (size_t)(r0 + row) * 128 + kc + col);
            XT[col + 0][row] = v.x;
            XT[col + 1][row] = v.y;
            XT[col + 2][row] = v.z;
            XT[col + 3][row] = v.w;
        }
        __syncthreads();
#pragma unroll
        for (int kk = 0; kk < 32; ++kk) {
            float4 a4 = *(const float4*)(&XT[kk][rg * 4]);
            float4 w4 = *(const float4*)(Wc + kk * 64 + tx * 4);
            acc[0][0] = fmaf(a4.x, w4.x, acc[0][0]); acc[0][1] = fmaf(a4.x, w4.y, acc[0][1]);
            acc[0][2] = fmaf(a4.x, w4.z, acc[0][2]); acc[0][3] = fmaf(a4.x, w4.w, acc[0][3]);
            acc[1][0] = fmaf(a4.y, w4.x, acc[1][0]); acc[1][1] = fmaf(a4.y, w4.y, acc[1][1]);
            acc[1][2] = fmaf(a4.y, w4.z, acc[1][2]); acc[1][3] = fmaf(a4.y, w4.w, acc[1][3]);
            acc[2][0] = fmaf(a4.z, w4.x, acc[2][0]); acc[2][1] = fmaf(a4.z, w4.y, acc[2][1]);
            acc[2][2] = fmaf(a4.z, w4.z, acc[2][2]); acc[2][3] = fmaf(a4.z, w4.w, acc[2][3]);
            acc[3][0] = fmaf(a4.w, w4.x, acc[3][0]); acc[3][1] = fmaf(a4.w, w4.y, acc[3][1]);
            acc[3][2] = fmaf(a4.w, w4.z, acc[3][2]); acc[3][3] = fmaf(a4.w, w4.w, acc[3][3]);
        }
    }

    float b4[4];
#pragma unroll
    for (int q = 0; q < 4; ++q) {
        int c = c0 + tx * 4 + q;
        b4[q] = (c < OUTD) ? bias[c] : 0.f;
    }
#pragma unroll
    for (int i = 0; i < 4; ++i) {
        size_t n = (size_t)r0 + rg * 4 + i;
#pragma unroll
        for (int q = 0; q < 4; ++q) {
            int c = c0 + tx * 4 + q;
            if (c < OUTD) out[n * OUTD + c] = acc[i][q] + b4[q];
        }
    }
}

// ---------------- host ----------------
extern "C" void kernel_launch(void* const* d_in, const int* in_sizes, int n_in,
                              void* d_out, int out_size, void* d_ws, size_t ws_size,
                              hipStream_t stream) {
    const float* x_author = (const float*)d_in[0];
    const float* x_paper  = (const float*)d_in[1];
    const float* ntype    = (const float*)d_in[2];
    const float* W0  = (const float*)d_in[3];
    const float* al0 = (const float*)d_in[4];
    const float* ar0 = (const float*)d_in[5];
    const float* b0  = (const float*)d_in[6];
    const float* W1  = (const float*)d_in[7];
    const float* al1 = (const float*)d_in[8];
    const float* ar1 = (const float*)d_in[9];
    const float* b1  = (const float*)d_in[10];
    const float* ln1gb = (const float*)d_in[11];
    const float* attw  = (const float*)d_in[12];
    const float* attb  = (const float*)d_in[13];
    const float* ln2gb = (const float*)d_in[14];
    const float* fw1 = (const float*)d_in[15];
    const float* fb1 = (const float*)d_in[16];
    const float* fw2 = (const float*)d_in[17];
    const float* fb2 = (const float*)d_in[18];
    const float* linW = (const float*)d_in[19];
    const float* linb = (const float*)d_in[20];
    const int* srcW = (const int*)d_in[21];
    const int* dstW = (const int*)d_in[22];
    const int* srcC = (const int*)d_in[23];
    const int* dstC = (const int*)d_in[24];
    const int* srcR = (const int*)d_in[25];
    const int* dstR = (const int*)d_in[26];
    float* out = (float*)d_out;

    // ---- workspace carve-up ----
    float* ws = (float*)d_ws;
    size_t off = 0;
    float* fsW = ws + off; off += (size_t)N_A * HID;
    float* fsC = ws + off; off += (size_t)N_P * HID;
    float* fsR = ws + off; off += (size_t)N_P * HID;
    float* elw = ws + off; off += (size_t)N_A * NH;
    float* erw = ws + off; off += (size_t)N_P * NH;
    float* elc = ws + off; off += (size_t)N_P * NH;
    float* erc = ws + off; off += (size_t)N_P * NH;
    float* elr = ws + off; off += (size_t)N_P * NH;
    float* err = ws + off; off += (size_t)N_A * NH;
    float* oa0 = ws + off; off += (size_t)N_A * HID;
    float* op0 = ws + off; off += (size_t)N_P * HID;
    float* hf  = ws + off; off += (size_t)N_P * 2 * HID;
    int* ccnt  = (int*)(ws + off); off += 3 * NB * 256;
    int* coffs = (int*)(ws + off); off += 3 * NB * 256;
    int* crow  = (int*)(ws + off); off += 3 * 257 + 1;
    int* row   = (int*)(ws + off); off += 3 * 16385 + 1;
    int* ebW  = (int*)(ws + off); off += NE;
    int* ebC  = (int*)(ws + off); off += NE;
    int* ebR  = (int*)(ws + off); off += NE;
    int* esW  = (int*)(ws + off); off += NE;
    int* esC  = (int*)(ws + off); off += NE;
    int* esR  = (int*)(ws + off); off += NE;

    const int* rowW = row;
    const int* rowC = row + 16385;
    const int* rowR = row + 2 * 16385;

    const float* ntA = ntype;            // author scale row (128)
    const float* ntP = ntype + IN_D;     // paper scale row

    // ---- layer job tables (layer 0 reads raw x, scaled by NT on load) ----
    GemmJobs j0{};
    j0.X[0] = x_author; j0.W[0] = W0;                  j0.NT[0] = ntA;
    j0.F[0] = fsW; j0.EL[0] = elw; j0.ER[0] = nullptr; j0.AL[0] = al0;       j0.AR[0] = nullptr;
    j0.X[1] = x_paper;  j0.W[1] = W0;                  j0.NT[1] = ntP;
    j0.F[1] = nullptr; j0.EL[1] = nullptr; j0.ER[1] = erw; j0.AL[1] = nullptr; j0.AR[1] = ar0;
    j0.X[2] = x_paper;  j0.W[2] = W0 + IN_D * HID;     j0.NT[2] = ntP;
    j0.F[2] = fsC; j0.EL[2] = elc; j0.ER[2] = erc;     j0.AL[2] = al0 + 64;  j0.AR[2] = ar0 + 64;
    j0.X[3] = x_paper;  j0.W[3] = W0 + 2 * IN_D * HID; j0.NT[3] = ntP;
    j0.F[3] = fsR; j0.EL[3] = elr; j0.ER[3] = nullptr; j0.AL[3] = al0 + 128; j0.AR[3] = nullptr;
    j0.X[4] = x_author; j0.W[4] = W0 + 2 * IN_D * HID; j0.NT[4] = ntA;
    j0.F[4] = nullptr; j0.EL[4] = nullptr; j0.ER[4] = err; j0.AL[4] = nullptr; j0.AR[4] = ar0 + 128;

    // layer 1: revw GAT (jobs 3,4 of the old table) is DEAD — oa1 never used.
    GemmJobs j1{};
    j1.X[0] = oa0; j1.W[0] = W1;                   j1.NT[0] = nullptr;
    j1.F[0] = fsW; j1.EL[0] = elw; j1.ER[0] = nullptr; j1.AL[0] = al1;       j1.AR[0] = nullptr;
    j1.X[1] = op0; j1.W[1] = W1;                   j1.NT[1] = nullptr;
    j1.F[1] = nullptr; j1.EL[1] = nullptr; j1.ER[1] = erw; j1.AL[1] = nullptr; j1.AR[1] = ar1;
    j1.X[2] = op0; j1.W[2] = W1 + HID * HID;       j1.NT[2] = nullptr;
    j1.F[2] = fsC; j1.EL[2] = elc; j1.ER[2] = erc;     j1.AL[2] = al1 + 64;  j1.AR[2] = ar1 + 64;

    AggArgs a0{};
    a0.t[0] = {rowW, esW, elw, erw, fsW};
    a0.t[1] = {rowC, esC, elc, erc, fsC};
    a0.t[2] = {rowR, esR, elr, err, fsR};
    a0.b = b0; a0.op = op0; a0.oa = oa0;
    AggArgs a1 = a0;
    a1.b = b1; a1.op = nullptr; a1.oa = nullptr;
    a1.hf = hf;
    a1.ln1gb = ln1gb; a1.aw = attw; a1.ab = attb; a1.ln2gb = ln2gb;
    a1.fw1 = fw1; a1.fb1 = fb1; a1.fw2 = fw2; a1.fb2 = fb2;

    // ---- launches ----
    // CSR build (edge lists constant across layers): two-level partition
    k_chist<<<dim3(NB, 3), 256, 0, stream>>>(dstW, dstC, dstR, ccnt);
    k_coffs<<<1, 768, 0, stream>>>(ccnt, coffs, crow);
    k_cscatter<<<dim3(NB, 3), 256, 0, stream>>>(srcW, dstW, srcC, dstC, srcR, dstR,
                                                coffs, ebW, ebC, ebR);
    k_fine<<<dim3(256, 3), 256, 0, stream>>>(crow, ebW, ebC, ebR, row, esW, esC, esR);

    // layer 0 (ntype scale folded into X load)
    k_gemm<IN_D, 0><<<dim3(N_A / 64, 1, 5), 256, 0, stream>>>(j0);
    k_agg<0><<<(N_P + N_A) / 4, 256, 0, stream>>>(a0);

    // layer 1 (relu folded into GEMM X loads; dead revw jobs removed;
    // agg fuses l2-normalize + transformer constant, writes hf directly)
    k_gemm<HID, 1><<<dim3(N_A / 64, 1, 3), 256, 0, stream>>>(j1);
    k_agg<1><<<N_P / 4, 256, 0, stream>>>(a1);

    // output GEMM
    k_gemm_out<<<dim3(N_P / 64, (OUTD + 63) / 64), 256, 0, stream>>>(hf, linW, linb, out);
}